// Round 3
// baseline (1131.637 us; speedup 1.0000x reference)
//
#include <hip/hip_runtime.h>

#define N_NODES 20000
#define N_EDGES 100000
#define CIN     64
#define A_DIM   32
#define CCH     256
#define NBOX    128
#define FD      1024
#define HID     1024
#define OUT_STRIDE 2048

typedef __attribute__((ext_vector_type(8))) short          short8;
typedef __attribute__((ext_vector_type(8))) unsigned short ushort8;
typedef __attribute__((ext_vector_type(4))) unsigned short ushort4v;
typedef __attribute__((ext_vector_type(4))) float          floatx4;

__device__ __forceinline__ unsigned short f2bf(float f) {
    unsigned int u = __float_as_uint(f);
    u += 0x7fff + ((u >> 16) & 1);
    return (unsigned short)(u >> 16);
}
__device__ __forceinline__ float bf2f(unsigned short h) {
    return __uint_as_float(((unsigned int)h) << 16);
}

// async global->LDS, 16B per lane; LDS dest is wave-uniform base + lane*16
__device__ __forceinline__ void glds16(const unsigned short* g, unsigned short* l) {
    __builtin_amdgcn_global_load_lds(
        (const __attribute__((address_space(1))) unsigned int*)g,
        (__attribute__((address_space(3))) unsigned int*)l,
        16, 0, 0);
}

// ---------------------------------------------------------------------------
// Dense MFMA GEMM, 128x128 tile, BK=32, m97-style global_load_lds staging.
// A = [seg0 (C0 cols) | seg1] rows, both bf16. B = bf16 Wt[n][k].
// Epilogue: (+bias, relu opt) -> fp32 out and/or bf16 out.
// XCD-aware bijective blockIdx swizzle keeps a row-panel's column-blocks on
// one XCD's L2.
// ---------------------------------------------------------------------------
__global__ __launch_bounds__(256) void mfma_dense(
    const unsigned short* __restrict__ src0b, int s0, int o0, int C0,
    const unsigned short* __restrict__ src1b, int s1, int o1,
    const unsigned short* __restrict__ Wt, const float* __restrict__ bias,
    int do_relu,
    float* __restrict__ outf, int sof, int oof,
    unsigned short* __restrict__ outb, int sob, int oob,
    int M, int K, int nbc)
{
    __shared__ __align__(16) unsigned short As[128 * 32];
    __shared__ __align__(16) unsigned short Bs[128 * 32];

    const int tid  = threadIdx.x;

    // bijective XCD swizzle (works for any gridDim)
    const int nwg  = gridDim.x;
    const int q8   = nwg >> 3, r8 = nwg & 7;
    const int xcd  = blockIdx.x & 7, boff = blockIdx.x >> 3;
    const int bid  = (xcd < r8 ? xcd * (q8 + 1)
                               : r8 * (q8 + 1) + (xcd - r8) * q8) + boff;

    const int rb   = bid / nbc, cb = bid % nbc;
    const int r0   = rb * 128, c0 = cb * 128;
    const int wave = tid >> 6, lane = tid & 63;
    const int quad = lane >> 4, l16 = lane & 15;
    const int wm   = (wave & 1) * 64, wn = (wave >> 1) * 64;

    // staging slot geometry: slot g = i*256 + tid covers LDS bytes [g*16, g*16+16)
    // row = g>>2 (64B rows), k-chunk = (g&3)*8 bf16
    int grow[2], brow[2], kch[2];
    #pragma unroll
    for (int i = 0; i < 2; ++i) {
        const int g  = i * 256 + tid;
        const int rr = g >> 2;
        kch[i] = (g & 3) << 3;
        int gr2 = r0 + rr;
        if (gr2 >= M) gr2 = M - 1;
        grow[i] = gr2;
        brow[i] = c0 + rr;
    }
    unsigned short* AsW = As + wave * 512;   // +i*2048 shorts per inst
    unsigned short* BsW = Bs + wave * 512;

    floatx4 acc[4][4];
    #pragma unroll
    for (int i = 0; i < 4; ++i)
        #pragma unroll
        for (int j = 0; j < 4; ++j) acc[i][j] = (floatx4){0.f, 0.f, 0.f, 0.f};

    for (int k0 = 0; k0 < K; k0 += 32) {
        #pragma unroll
        for (int i = 0; i < 2; ++i) {
            const int kk = k0 + kch[i];
            const unsigned short* ga = (kk < C0)
                ? src0b + (long)grow[i] * s0 + o0 + kk
                : src1b + (long)grow[i] * s1 + o1 + (kk - C0);
            glds16(ga, AsW + i * 2048);
            glds16(Wt + (long)brow[i] * K + k0 + kch[i], BsW + i * 2048);
        }
        __syncthreads();

        short8 af[4], bfr[4];
        #pragma unroll
        for (int mt = 0; mt < 4; ++mt)
            af[mt] = *(const short8*)(&As[(wm + mt * 16 + l16) * 32 + quad * 8]);
        #pragma unroll
        for (int nt = 0; nt < 4; ++nt)
            bfr[nt] = *(const short8*)(&Bs[(wn + nt * 16 + l16) * 32 + quad * 8]);
        #pragma unroll
        for (int mt = 0; mt < 4; ++mt)
            #pragma unroll
            for (int nt = 0; nt < 4; ++nt)
                acc[mt][nt] = __builtin_amdgcn_mfma_f32_16x16x32_bf16(
                    af[mt], bfr[nt], acc[mt][nt], 0, 0, 0);
        __syncthreads();
    }

    #pragma unroll
    for (int nt = 0; nt < 4; ++nt) {
        const int gc = c0 + wn + nt * 16 + l16;
        const float bv = bias ? bias[gc] : 0.f;
        #pragma unroll
        for (int mt = 0; mt < 4; ++mt) {
            #pragma unroll
            for (int reg = 0; reg < 4; ++reg) {
                const int grr = r0 + wm + mt * 16 + quad * 4 + reg;
                if (grr < M) {
                    float v = acc[mt][nt][reg] + bv;
                    if (do_relu) v = fmaxf(v, 0.f);
                    if (outf) outf[(long)grr * sof + oof + gc] = v;
                    if (outb) outb[(long)grr * sob + oob + gc] = f2bf(v);
                }
            }
        }
    }
}

// ---------------------------------------------------------------------------
// fp32 -> bf16 bulk convert (n multiple of 4)
// ---------------------------------------------------------------------------
__global__ void f32_to_bf16(const float* __restrict__ in,
                            unsigned short* __restrict__ out, int n4) {
    int i = blockIdx.x * blockDim.x + threadIdx.x;
    if (i < n4) {
        float4 v = ((const float4*)in)[i];
        ushort4v h = (ushort4v){f2bf(v.x), f2bf(v.y), f2bf(v.z), f2bf(v.w)};
        ((ushort4v*)out)[i] = h;
    }
}

// ---------------------------------------------------------------------------
// Aggregation with fused R: one wave per 4 dst nodes.
// f_out[d] = sum_e relu(P[d] + Q[src] + ea[e]@We + b) * ew[e]  (+ residual).
// We (32x256 fp32) column-slice lives in 128 VGPRs per lane; ea row is a
// wave-uniform broadcast load. Edges CSR-sorted by dst -> no atomics.
// Writes fp32 into out (final feats_cat) AND bf16 into nfbf (GEMM A input).
// ---------------------------------------------------------------------------
#define NPW 4
__global__ __launch_bounds__(256) void agg_kernel(
    const unsigned short* __restrict__ pq,   // [N,512] bf16: [P | Q]
    const int* __restrict__ rowptr,
    const int* __restrict__ ssrc,
    const float* __restrict__ sew,
    const int* __restrict__ seid,
    const float* __restrict__ ea,            // [E,32] fp32
    const float* __restrict__ We,            // [32,256] fp32 edge-weight slice
    const float* __restrict__ outbase,       // residual source
    const float* __restrict__ bias,
    float* __restrict__ out, int fofs, int rofs,
    unsigned short* __restrict__ nfbf, int nofs)
{
    const int wvid = (blockIdx.x * blockDim.x + threadIdx.x) >> 6;
    const int lane = threadIdx.x & 63;
    const int n0 = wvid * NPW;
    if (n0 >= N_NODES) return;
    const int c = lane * 4;

    // wv[k] = We[k][c..c+3]; coalesced per-k row loads, held in registers.
    float4 wv[32];
    #pragma unroll
    for (int k = 0; k < 32; ++k)
        wv[k] = *(const float4*)(We + k * 256 + c);

    const float4 bb = *(const float4*)(bias + c);

    for (int ni = 0; ni < NPW; ++ni) {
        const int wid = n0 + ni;
        const ushort4v p4 = *(const ushort4v*)(pq + (long)wid * 512 + c);
        const float pb0 = bf2f(p4[0]) + bb.x, pb1 = bf2f(p4[1]) + bb.y;
        const float pb2 = bf2f(p4[2]) + bb.z, pb3 = bf2f(p4[3]) + bb.w;
        float a0 = 0.f, a1 = 0.f, a2 = 0.f, a3 = 0.f;

        const int sEnd = rowptr[wid + 1];
        for (int s = rowptr[wid]; s < sEnd; ++s) {
            const int   srcn = ssrc[s];
            const float wgt  = sew[s];
            const int   e    = seid[s];
            const ushort4v q4 = *(const ushort4v*)(pq + (long)srcn * 512 + 256 + c);
            const float4* ep = (const float4*)(ea + (long)e * 32);
            float r0 = 0.f, r1 = 0.f, r2 = 0.f, r3 = 0.f;
            #pragma unroll
            for (int kk = 0; kk < 8; ++kk) {
                const float4 e4 = ep[kk];
                const float4 wA = wv[4 * kk + 0], wB = wv[4 * kk + 1];
                const float4 wC = wv[4 * kk + 2], wD = wv[4 * kk + 3];
                r0 += e4.x * wA.x + e4.y * wB.x + e4.z * wC.x + e4.w * wD.x;
                r1 += e4.x * wA.y + e4.y * wB.y + e4.z * wC.y + e4.w * wD.y;
                r2 += e4.x * wA.z + e4.y * wB.z + e4.z * wC.z + e4.w * wD.z;
                r3 += e4.x * wA.w + e4.y * wB.w + e4.z * wC.w + e4.w * wD.w;
            }
            a0 += fmaxf(pb0 + bf2f(q4[0]) + r0, 0.f) * wgt;
            a1 += fmaxf(pb1 + bf2f(q4[1]) + r1, 0.f) * wgt;
            a2 += fmaxf(pb2 + bf2f(q4[2]) + r2, 0.f) * wgt;
            a3 += fmaxf(pb3 + bf2f(q4[3]) + r3, 0.f) * wgt;
        }
        if (rofs >= 0) {
            const float4 f4 = *(const float4*)(outbase + (long)wid * OUT_STRIDE + rofs + c);
            a0 += f4.x; a1 += f4.y; a2 += f4.z; a3 += f4.w;
        }
        float4 o; o.x = a0; o.y = a1; o.z = a2; o.w = a3;
        *(float4*)(out + (long)wid * OUT_STRIDE + fofs + c) = o;
        ushort4v hb = (ushort4v){f2bf(a0), f2bf(a1), f2bf(a2), f2bf(a3)};
        *(ushort4v*)(nfbf + (long)wid * FD + nofs + c) = hb;
    }
}

// ---------------------------------------------------------------------------
// Weight prep
// ---------------------------------------------------------------------------
// Wpq[n][k]: n<256 -> W0-W1 column n; n>=256 -> W1 column n-256.  W is [2F+32,256].
__global__ void wpq_prep(const float* __restrict__ W, unsigned short* __restrict__ Wpq, int F) {
    int i = blockIdx.x * blockDim.x + threadIdx.x;
    if (i < 512 * F) {
        int nn = i / F, k = i % F;
        float v = (nn < 256) ? (W[k * 256 + nn] - W[(F + k) * 256 + nn])
                             : W[(F + k) * 256 + (nn - 256)];
        Wpq[(long)nn * F + k] = f2bf(v);
    }
}

// 3 ResBlock wpq preps in one launch (blockIdx.y = block index, F=256)
__global__ void wpq_prep3(const float* __restrict__ W, unsigned short* __restrict__ Wpq) {
    const float* Wi = W + (long)blockIdx.y * 544 * 256;
    unsigned short* Wo = Wpq + (long)blockIdx.y * 512 * 256;
    int i = blockIdx.x * blockDim.x + threadIdx.x;
    if (i < 512 * 256) {
        int nn = i / 256, k = i % 256;
        float v = (nn < 256) ? (Wi[k * 256 + nn] - Wi[(256 + k) * 256 + nn])
                             : Wi[(256 + k) * 256 + (nn - 256)];
        Wo[(long)nn * 256 + k] = f2bf(v);
    }
}

__global__ void transpose_w(const float* __restrict__ W, unsigned short* __restrict__ Wt,
                            int K, int N) {
    int i = blockIdx.x * blockDim.x + threadIdx.x;
    if (i < K * N) {
        int k = i / N, n = i % N;
        Wt[(long)n * K + k] = f2bf(W[i]);
    }
}

// 3 W_sup transposes (512x256 each) in one launch (blockIdx.y = block index)
__global__ void transpose_w3(const float* __restrict__ W, unsigned short* __restrict__ Wt) {
    const float* Wi = W + (long)blockIdx.y * 512 * 256;
    unsigned short* Wo = Wt + (long)blockIdx.y * 256 * 512;
    int i = blockIdx.x * blockDim.x + threadIdx.x;
    if (i < 512 * 256) {
        int k = i / 256, n = i % 256;
        Wo[(long)n * 512 + k] = f2bf(Wi[i]);
    }
}

// ---------------------------------------------------------------------------
// CSR build
// ---------------------------------------------------------------------------
__global__ void zero_int(int* p, int n) {
    int i = blockIdx.x * blockDim.x + threadIdx.x;
    if (i < n) p[i] = 0;
}
__global__ void hist_kernel(const int* __restrict__ keys, int n, int* __restrict__ cnt) {
    int i = blockIdx.x * blockDim.x + threadIdx.x;
    if (i < n) atomicAdd(&cnt[keys[i]], 1);
}
__global__ __launch_bounds__(1024) void scan_kernel(const int* __restrict__ cnt,
                                                    int* __restrict__ rowptr,
                                                    int* __restrict__ ofs, int n) {
    __shared__ int part[1024];
    const int tid = threadIdx.x;
    const int chunk = (n + 1023) >> 10;
    int s = 0;
    for (int j = 0; j < chunk; ++j) {
        int i = tid * chunk + j;
        if (i < n) s += cnt[i];
    }
    part[tid] = s; __syncthreads();
    for (int d = 1; d < 1024; d <<= 1) {
        int v = (tid >= d) ? part[tid - d] : 0;
        __syncthreads();
        part[tid] += v;
        __syncthreads();
    }
    int run = (tid > 0) ? part[tid - 1] : 0;
    for (int j = 0; j < chunk; ++j) {
        int i = tid * chunk + j;
        if (i < n) { rowptr[i] = run; ofs[i] = run; run += cnt[i]; }
    }
    if (tid == 1023) rowptr[n] = part[1023];
}
__global__ void scatter_edges(const int* __restrict__ src, const int* __restrict__ dst,
                              const float* __restrict__ ew, int* __restrict__ ofs,
                              int* __restrict__ ssrc, float* __restrict__ sew,
                              int* __restrict__ seid) {
    int e = blockIdx.x * blockDim.x + threadIdx.x;
    if (e < N_EDGES) {
        int pos = atomicAdd(&ofs[dst[e]], 1);
        ssrc[pos] = src[e];
        sew[pos]  = ew[e];
        seid[pos] = e;
    }
}
__global__ void scatter_box(const int* __restrict__ bbox, int* __restrict__ ofs,
                            int* __restrict__ snode) {
    int i = blockIdx.x * blockDim.x + threadIdx.x;
    if (i < N_NODES) {
        int pos = atomicAdd(&ofs[bbox[i]], 1);
        snode[pos] = i;
    }
}

// ---------------------------------------------------------------------------
// Box mean via CSR (no atomics). Emits fp32 into out_super and bf16 fsmean.
// ---------------------------------------------------------------------------
__global__ __launch_bounds__(256) void box_mean_csr(
    const unsigned short* __restrict__ fsbf, const int* __restrict__ bptr,
    const int* __restrict__ snode, float* __restrict__ out_super,
    unsigned short* __restrict__ fsmeanb)
{
    const int b = blockIdx.x >> 2;
    const int c = ((blockIdx.x & 3) << 8) + threadIdx.x;
    const int s0 = bptr[b], s1 = bptr[b + 1];
    float sum = 0.f;
    for (int s = s0; s < s1; ++s)
        sum += bf2f(fsbf[(long)snode[s] * FD + c]);
    const float mean = sum / fmaxf((float)(s1 - s0), 1.f);
    out_super[(long)b * OUT_STRIDE + HID + c] = mean;
    fsmeanb[(long)b * FD + c] = f2bf(mean);
}

// ---------------------------------------------------------------------------
extern "C" void kernel_launch(void* const* d_in, const int* in_sizes, int n_in,
                              void* d_out, int out_size, void* d_ws, size_t ws_size,
                              hipStream_t stream) {
    const float* x      = (const float*)d_in[0];
    const int*   edges  = (const int*)d_in[1];
    const float* ew     = (const float*)d_in[2];
    const float* ea     = (const float*)d_in[3];
    const int*   bbox   = (const int*)d_in[4];
    const float* W_msg0 = (const float*)d_in[6];
    const float* b_msg0 = (const float*)d_in[7];
    const float* W_sup0 = (const float*)d_in[8];
    const float* b_sup0 = (const float*)d_in[9];
    const float* W_msg  = (const float*)d_in[10];
    const float* b_msg  = (const float*)d_in[11];
    const float* W_sup  = (const float*)d_in[12];
    const float* b_sup  = (const float*)d_in[13];
    const float* W_fuse = (const float*)d_in[14];
    const float* b_fuse = (const float*)d_in[15];
    const float* W_fsup = (const float*)d_in[16];
    const float* b_fsup = (const float*)d_in[17];

    float* out       = (float*)d_out;
    float* out_super = out + (long)N_NODES * OUT_STRIDE;

    // ---- workspace layout ----
    char* w = (char*)d_ws;
    auto alloc = [&](size_t bytes) { char* p = w; w += (bytes + 63) & ~63ULL; return p; };
    unsigned short* fsbf    = (unsigned short*)alloc((size_t)N_NODES * FD * 2);
    unsigned short* nfbf    = (unsigned short*)alloc((size_t)N_NODES * FD * 2);
    unsigned short* pq      = (unsigned short*)alloc((size_t)N_NODES * 512 * 2);
    unsigned short* xb      = (unsigned short*)alloc((size_t)N_NODES * CIN * 2);
    unsigned short* wpq0    = (unsigned short*)alloc((size_t)512 * CIN * 2);
    unsigned short* wpq     = (unsigned short*)alloc((size_t)3 * 512 * CCH * 2);
    unsigned short* wt_sup0 = (unsigned short*)alloc((size_t)256 * 320 * 2);
    unsigned short* wt_sup  = (unsigned short*)alloc((size_t)3 * 256 * 512 * 2);
    unsigned short* wt_fuse = (unsigned short*)alloc((size_t)1024 * 1024 * 2);
    unsigned short* wt_fsup = (unsigned short*)alloc((size_t)1024 * 1024 * 2);
    unsigned short* fsmeanb = (unsigned short*)alloc((size_t)NBOX * FD * 2);
    float* sew        = (float*)alloc((size_t)N_EDGES * 4);
    int* cnt          = (int*)alloc((size_t)(N_NODES + 1) * 4);
    int* rowptr       = (int*)alloc((size_t)(N_NODES + 1) * 4);
    int* ofs          = (int*)alloc((size_t)(N_NODES + 1) * 4);
    int* ssrc         = (int*)alloc((size_t)N_EDGES * 4);
    int* seid         = (int*)alloc((size_t)N_EDGES * 4);
    int* bcnt         = (int*)alloc(129 * 4);
    int* bptr         = (int*)alloc(129 * 4);
    int* bofs         = (int*)alloc(129 * 4);
    int* snode        = (int*)alloc((size_t)N_NODES * 4);

    const int* srcp = edges;
    const int* dstp = edges + N_EDGES;

    // ---- input bf16 conversion ----
    f32_to_bf16<<<(N_NODES * CIN / 4 + 255) / 256, 256, 0, stream>>>(x, xb, N_NODES * CIN / 4);

    // ---- weight prep ----
    wpq_prep<<<(512 * CIN + 255) / 256, 256, 0, stream>>>(W_msg0, wpq0, CIN);
    wpq_prep3<<<dim3((512 * CCH + 255) / 256, 3), 256, 0, stream>>>(W_msg, wpq);
    transpose_w<<<(320 * 256 + 255) / 256, 256, 0, stream>>>(W_sup0, wt_sup0, 320, 256);
    transpose_w3<<<dim3((512 * 256 + 255) / 256, 3), 256, 0, stream>>>(W_sup, wt_sup);
    transpose_w<<<(1024 * 1024 + 255) / 256, 256, 0, stream>>>(W_fuse, wt_fuse, 1024, 1024);
    transpose_w<<<(1024 * 1024 + 255) / 256, 256, 0, stream>>>(W_fsup, wt_fsup, 1024, 1024);

    // ---- CSR build (edges by dst; nodes by box) ----
    zero_int<<<(N_NODES + 256) / 256, 256, 0, stream>>>(cnt, N_NODES + 1);
    zero_int<<<1, 256, 0, stream>>>(bcnt, 129);
    hist_kernel<<<(N_EDGES + 255) / 256, 256, 0, stream>>>(dstp, N_EDGES, cnt);
    hist_kernel<<<(N_NODES + 255) / 256, 256, 0, stream>>>(bbox, N_NODES, bcnt);
    scan_kernel<<<1, 1024, 0, stream>>>(cnt, rowptr, ofs, N_NODES);
    scan_kernel<<<1, 1024, 0, stream>>>(bcnt, bptr, bofs, NBOX);
    scatter_edges<<<(N_EDGES + 255) / 256, 256, 0, stream>>>(srcp, dstp, ew, ofs, ssrc, sew, seid);
    scatter_box<<<(N_NODES + 255) / 256, 256, 0, stream>>>(bbox, bofs, snode);

    const int GRB = (N_NODES + 127) / 128;   // 157
    const int AGG_GRID = (N_NODES / NPW + 3) / 4;   // 1250 blocks, 4 waves each

    // ---- head block ----
    mfma_dense<<<GRB * 4, 256, 0, stream>>>(xb, CIN, 0, CIN,
        nullptr, 0, 0, wpq0, nullptr, 0,
        nullptr, 0, 0, pq, 512, 0, N_NODES, CIN, 4);
    agg_kernel<<<AGG_GRID, 256, 0, stream>>>(pq, rowptr, ssrc, sew, seid, ea,
        W_msg0 + 2 * CIN * 256, out, b_msg0, out, HID, -1, nfbf, 0);
    mfma_dense<<<GRB * 2, 256, 0, stream>>>(nfbf, FD, 0, CCH,
        xb, CIN, 0, wt_sup0, b_sup0, 1,
        nullptr, 0, 0, fsbf, FD, 0, N_NODES, CCH + CIN, 2);

    // ---- ResBlocks ----
    for (int i = 0; i < 3; ++i) {
        const int fi = HID + CCH * i, fo = HID + CCH * (i + 1);
        mfma_dense<<<GRB * 4, 256, 0, stream>>>(nfbf, FD, CCH * i, CCH,
            nullptr, 0, 0, wpq + (long)i * 512 * CCH, nullptr, 0,
            nullptr, 0, 0, pq, 512, 0, N_NODES, CCH, 4);
        agg_kernel<<<AGG_GRID, 256, 0, stream>>>(pq, rowptr, ssrc, sew, seid, ea,
            W_msg + (long)i * 544 * 256 + 2 * CCH * 256, out, b_msg + i * CCH,
            out, fo, fi, nfbf, CCH * (i + 1));
        mfma_dense<<<GRB * 2, 256, 0, stream>>>(nfbf, FD, CCH * (i + 1), CCH,
            fsbf, FD, CCH * i, wt_sup + (long)i * 256 * 512, b_sup + i * CCH, 1,
            nullptr, 0, 0, fsbf, FD, CCH * (i + 1), N_NODES, 2 * CCH, 2);
    }

    // ---- fusion ----
    mfma_dense<<<GRB * 8, 256, 0, stream>>>(nfbf, FD, 0, FD,
        nullptr, 0, 0, wt_fuse, b_fuse, 1,
        out, OUT_STRIDE, 0, nullptr, 0, 0, N_NODES, FD, 8);

    // ---- super path ----
    box_mean_csr<<<NBOX * 4, 256, 0, stream>>>(fsbf, bptr, snode, out_super, fsmeanb);
    mfma_dense<<<8, 256, 0, stream>>>(fsmeanb, FD, 0, FD,
        nullptr, 0, 0, wt_fsup, b_fsup, 1,
        out_super, OUT_STRIDE, 0, nullptr, 0, 0, NBOX, FD, 8);
}

// Round 4
// 960.652 us; speedup vs baseline: 1.1780x; 1.1780x over previous
//
#include <hip/hip_runtime.h>

#define N_NODES 20000
#define N_EDGES 100000
#define CIN     64
#define A_DIM   32
#define CCH     256
#define NBOX    128
#define FD      1024
#define HID     1024
#define OUT_STRIDE 2048

typedef __attribute__((ext_vector_type(8))) short          short8;
typedef __attribute__((ext_vector_type(8))) unsigned short ushort8;
typedef __attribute__((ext_vector_type(4))) unsigned short ushort4v;
typedef __attribute__((ext_vector_type(4))) float          floatx4;

__device__ __forceinline__ unsigned short f2bf(float f) {
    unsigned int u = __float_as_uint(f);
    u += 0x7fff + ((u >> 16) & 1);
    return (unsigned short)(u >> 16);
}
__device__ __forceinline__ float bf2f(unsigned short h) {
    return __uint_as_float(((unsigned int)h) << 16);
}

// async global->LDS, 16B per lane; LDS dest is wave-uniform base + lane*16
__device__ __forceinline__ void glds16(const unsigned short* g, unsigned short* l) {
    __builtin_amdgcn_global_load_lds(
        (const __attribute__((address_space(1))) unsigned int*)g,
        (__attribute__((address_space(3))) unsigned int*)l,
        16, 0, 0);
}

// ---------------------------------------------------------------------------
// Dense MFMA GEMM, 128x128 tile, BK=32, m97-style global_load_lds staging.
// A = [seg0 (C0 cols) | seg1] rows, both bf16; optional row remap on seg0 via
// ridx0 (seg1 unremapped). B = bf16 Wt[n][k]. Epilogue: (+bias, relu opt) ->
// fp32 out and/or bf16 out; rmode packs bf16 rows 8-per-out-row (R matrix,
// sequential in row index for the agg's streaming read).
// XCD-aware bijective blockIdx swizzle keeps a row-panel's column-blocks on
// one XCD's L2.
// ---------------------------------------------------------------------------
__global__ __launch_bounds__(256) void mfma_dense(
    const unsigned short* __restrict__ src0b, int s0, int o0, int C0,
    const int* __restrict__ ridx0,
    const unsigned short* __restrict__ src1b, int s1, int o1,
    const unsigned short* __restrict__ Wt, const float* __restrict__ bias,
    int do_relu,
    float* __restrict__ outf, int sof, int oof,
    unsigned short* __restrict__ outb, int sob, int oob, int rmode,
    int M, int K, int nbc)
{
    __shared__ __align__(16) unsigned short As[128 * 32];
    __shared__ __align__(16) unsigned short Bs[128 * 32];

    const int tid  = threadIdx.x;

    // bijective XCD swizzle (works for any gridDim)
    const int nwg  = gridDim.x;
    const int q8   = nwg >> 3, r8 = nwg & 7;
    const int xcd  = blockIdx.x & 7, boff = blockIdx.x >> 3;
    const int bid  = (xcd < r8 ? xcd * (q8 + 1)
                               : r8 * (q8 + 1) + (xcd - r8) * q8) + boff;

    const int rb   = bid / nbc, cb = bid % nbc;
    const int r0   = rb * 128, c0 = cb * 128;
    const int wave = tid >> 6, lane = tid & 63;
    const int quad = lane >> 4, l16 = lane & 15;
    const int wm   = (wave & 1) * 64, wn = (wave >> 1) * 64;

    // staging slot geometry: slot g = i*256 + tid covers LDS bytes [g*16, g*16+16)
    // row = g>>2 (64B rows), k-chunk = (g&3)*8 bf16
    int arow[2], grow[2], brow[2], kch[2];
    #pragma unroll
    for (int i = 0; i < 2; ++i) {
        const int g  = i * 256 + tid;
        const int rr = g >> 2;
        kch[i] = (g & 3) << 3;
        int gr2 = r0 + rr;
        if (gr2 >= M) gr2 = M - 1;
        grow[i] = gr2;
        arow[i] = ridx0 ? ridx0[gr2] : gr2;
        brow[i] = c0 + rr;
    }
    unsigned short* AsW = As + wave * 512;   // +i*2048 shorts per inst
    unsigned short* BsW = Bs + wave * 512;

    floatx4 acc[4][4];
    #pragma unroll
    for (int i = 0; i < 4; ++i)
        #pragma unroll
        for (int j = 0; j < 4; ++j) acc[i][j] = (floatx4){0.f, 0.f, 0.f, 0.f};

    for (int k0 = 0; k0 < K; k0 += 32) {
        #pragma unroll
        for (int i = 0; i < 2; ++i) {
            const int kk = k0 + kch[i];
            const unsigned short* ga = (kk < C0)
                ? src0b + (long)arow[i] * s0 + o0 + kk
                : src1b + (long)grow[i] * s1 + o1 + (kk - C0);
            glds16(ga, AsW + i * 2048);
            glds16(Wt + (long)brow[i] * K + k0 + kch[i], BsW + i * 2048);
        }
        __syncthreads();

        short8 af[4], bfr[4];
        #pragma unroll
        for (int mt = 0; mt < 4; ++mt)
            af[mt] = *(const short8*)(&As[(wm + mt * 16 + l16) * 32 + quad * 8]);
        #pragma unroll
        for (int nt = 0; nt < 4; ++nt)
            bfr[nt] = *(const short8*)(&Bs[(wn + nt * 16 + l16) * 32 + quad * 8]);
        #pragma unroll
        for (int mt = 0; mt < 4; ++mt)
            #pragma unroll
            for (int nt = 0; nt < 4; ++nt)
                acc[mt][nt] = __builtin_amdgcn_mfma_f32_16x16x32_bf16(
                    af[mt], bfr[nt], acc[mt][nt], 0, 0, 0);
        __syncthreads();
    }

    #pragma unroll
    for (int nt = 0; nt < 4; ++nt) {
        const int gc = c0 + wn + nt * 16 + l16;
        const float bv = bias ? bias[gc] : 0.f;
        #pragma unroll
        for (int mt = 0; mt < 4; ++mt) {
            #pragma unroll
            for (int reg = 0; reg < 4; ++reg) {
                const int grr = r0 + wm + mt * 16 + quad * 4 + reg;
                if (grr < M) {
                    float v = acc[mt][nt][reg] + bv;
                    if (do_relu) v = fmaxf(v, 0.f);
                    if (outf) outf[(long)grr * sof + oof + gc] = v;
                    if (outb) {
                        long idx = rmode
                            ? ((long)(grr >> 3) * 4096 + (grr & 7) * 256 + gc)
                            : ((long)grr * sob + oob + gc);
                        outb[idx] = f2bf(v);
                    }
                }
            }
        }
    }
}

// ---------------------------------------------------------------------------
// fp32 -> bf16 bulk convert (n multiple of 4)
// ---------------------------------------------------------------------------
__global__ void f32_to_bf16(const float* __restrict__ in,
                            unsigned short* __restrict__ out, int n4) {
    int i = blockIdx.x * blockDim.x + threadIdx.x;
    if (i < n4) {
        float4 v = ((const float4*)in)[i];
        ushort4v h = (ushort4v){f2bf(v.x), f2bf(v.y), f2bf(v.z), f2bf(v.w)};
        ((ushort4v*)out)[i] = h;
    }
}

// ---------------------------------------------------------------------------
// Aggregation: one wave per dst node. f_out[d] = sum_e relu(P[d]+Q[src]+R[e]+b)
// * ew[e]  (+ residual). Edges CSR-sorted by dst -> no atomics. One-deep
// software prefetch on the edge stream (loads for s+1 issue before compute
// of s) to break the serial gather-latency chain.
// Writes fp32 into out (final feats_cat) AND bf16 into nfbf (GEMM A input).
// ---------------------------------------------------------------------------
__global__ __launch_bounds__(256) void agg_kernel(
    const unsigned short* __restrict__ pq,   // [N,512] bf16: [P | Q]
    const int* __restrict__ rowptr,
    const int* __restrict__ ssrc,
    const float* __restrict__ sew,
    const float* __restrict__ outbase,       // R raw storage + residual source
    const float* __restrict__ bias,
    float* __restrict__ out, int fofs, int rofs,
    unsigned short* __restrict__ nfbf, int nofs)
{
    const int wid  = (blockIdx.x * blockDim.x + threadIdx.x) >> 6;
    const int lane = threadIdx.x & 63;
    if (wid >= N_NODES) return;
    const int c = lane * 4;

    const ushort4v p4 = *(const ushort4v*)(pq + (long)wid * 512 + c);
    const float4 bb = *(const float4*)(bias + c);
    float pb[4] = {bf2f(p4[0]) + bb.x, bf2f(p4[1]) + bb.y,
                   bf2f(p4[2]) + bb.z, bf2f(p4[3]) + bb.w};
    float acc[4] = {0.f, 0.f, 0.f, 0.f};

    int s = rowptr[wid];
    const int sEnd = rowptr[wid + 1];

    ushort4v q4n, r4n;
    float wn_ = 0.f;
    if (s < sEnd) {
        const int srcn = ssrc[s];
        wn_ = sew[s];
        q4n = *(const ushort4v*)(pq + (long)srcn * 512 + 256 + c);
        r4n = *(const ushort4v*)((const unsigned short*)(outbase +
                  (long)(s >> 3) * OUT_STRIDE) + (s & 7) * 256 + c);
    }
    while (s < sEnd) {
        const ushort4v q4 = q4n, r4 = r4n;
        const float wgt = wn_;
        ++s;
        if (s < sEnd) {
            const int srcn = ssrc[s];
            wn_ = sew[s];
            q4n = *(const ushort4v*)(pq + (long)srcn * 512 + 256 + c);
            r4n = *(const ushort4v*)((const unsigned short*)(outbase +
                      (long)(s >> 3) * OUT_STRIDE) + (s & 7) * 256 + c);
        }
        #pragma unroll
        for (int j = 0; j < 4; ++j)
            acc[j] += fmaxf(pb[j] + bf2f(q4[j]) + bf2f(r4[j]), 0.f) * wgt;
    }
    if (rofs >= 0) {
        const float4 f4 = *(const float4*)(outbase + (long)wid * OUT_STRIDE + rofs + c);
        acc[0] += f4.x; acc[1] += f4.y; acc[2] += f4.z; acc[3] += f4.w;
    }
    float4 o; o.x = acc[0]; o.y = acc[1]; o.z = acc[2]; o.w = acc[3];
    *(float4*)(out + (long)wid * OUT_STRIDE + fofs + c) = o;
    ushort4v hb = (ushort4v){f2bf(acc[0]), f2bf(acc[1]), f2bf(acc[2]), f2bf(acc[3])};
    *(ushort4v*)(nfbf + (long)wid * FD + nofs + c) = hb;
}

// ---------------------------------------------------------------------------
// Weight prep
// ---------------------------------------------------------------------------
// Wpq[n][k]: n<256 -> W0-W1 column n; n>=256 -> W1 column n-256.  W is [2F+32,256].
__global__ void wpq_prep(const float* __restrict__ W, unsigned short* __restrict__ Wpq, int F) {
    int i = blockIdx.x * blockDim.x + threadIdx.x;
    if (i < 512 * F) {
        int nn = i / F, k = i % F;
        float v = (nn < 256) ? (W[k * 256 + nn] - W[(F + k) * 256 + nn])
                             : W[(F + k) * 256 + (nn - 256)];
        Wpq[(long)nn * F + k] = f2bf(v);
    }
}

// 3 ResBlock wpq preps in one launch (blockIdx.y = block index, F=256)
__global__ void wpq_prep3(const float* __restrict__ W, unsigned short* __restrict__ Wpq) {
    const float* Wi = W + (long)blockIdx.y * 544 * 256;
    unsigned short* Wo = Wpq + (long)blockIdx.y * 512 * 256;
    int i = blockIdx.x * blockDim.x + threadIdx.x;
    if (i < 512 * 256) {
        int nn = i / 256, k = i % 256;
        float v = (nn < 256) ? (Wi[k * 256 + nn] - Wi[(256 + k) * 256 + nn])
                             : Wi[(256 + k) * 256 + (nn - 256)];
        Wo[(long)nn * 256 + k] = f2bf(v);
    }
}

__global__ void transpose_w(const float* __restrict__ W, unsigned short* __restrict__ Wt,
                            int K, int N) {
    int i = blockIdx.x * blockDim.x + threadIdx.x;
    if (i < K * N) {
        int k = i / N, n = i % N;
        Wt[(long)n * K + k] = f2bf(W[i]);
    }
}

// 3 W_sup transposes (512x256 each) in one launch (blockIdx.y = block index)
__global__ void transpose_w3(const float* __restrict__ W, unsigned short* __restrict__ Wt) {
    const float* Wi = W + (long)blockIdx.y * 512 * 256;
    unsigned short* Wo = Wt + (long)blockIdx.y * 256 * 512;
    int i = blockIdx.x * blockDim.x + threadIdx.x;
    if (i < 512 * 256) {
        int k = i / 256, n = i % 256;
        Wo[(long)n * 512 + k] = f2bf(Wi[i]);
    }
}

// 4 edge-weight transposes (32x256 -> 256x32) in one launch; blockIdx.y=0 is
// the head slice (from W_msg0), 1..3 are the ResBlock slices (from W_msg).
__global__ void wtr_prep(const float* __restrict__ W_msg0,
                         const float* __restrict__ W_msg,
                         unsigned short* __restrict__ wtr) {
    const int j = blockIdx.y;
    const float* Wi = (j == 0) ? (W_msg0 + 2 * CIN * 256)
                               : (W_msg + (long)(j - 1) * 544 * 256 + 2 * CCH * 256);
    unsigned short* Wo = wtr + (long)j * 256 * 32;
    int i = blockIdx.x * blockDim.x + threadIdx.x;
    if (i < 32 * 256) {
        int k = i / 256, n = i % 256;
        Wo[(long)n * 32 + k] = f2bf(Wi[i]);
    }
}

// ---------------------------------------------------------------------------
// CSR build
// ---------------------------------------------------------------------------
__global__ void zero_int(int* p, int n) {
    int i = blockIdx.x * blockDim.x + threadIdx.x;
    if (i < n) p[i] = 0;
}
__global__ void hist_kernel(const int* __restrict__ keys, int n, int* __restrict__ cnt) {
    int i = blockIdx.x * blockDim.x + threadIdx.x;
    if (i < n) atomicAdd(&cnt[keys[i]], 1);
}
__global__ __launch_bounds__(1024) void scan_kernel(const int* __restrict__ cnt,
                                                    int* __restrict__ rowptr,
                                                    int* __restrict__ ofs, int n) {
    __shared__ int part[1024];
    const int tid = threadIdx.x;
    const int chunk = (n + 1023) >> 10;
    int s = 0;
    for (int j = 0; j < chunk; ++j) {
        int i = tid * chunk + j;
        if (i < n) s += cnt[i];
    }
    part[tid] = s; __syncthreads();
    for (int d = 1; d < 1024; d <<= 1) {
        int v = (tid >= d) ? part[tid - d] : 0;
        __syncthreads();
        part[tid] += v;
        __syncthreads();
    }
    int run = (tid > 0) ? part[tid - 1] : 0;
    for (int j = 0; j < chunk; ++j) {
        int i = tid * chunk + j;
        if (i < n) { rowptr[i] = run; ofs[i] = run; run += cnt[i]; }
    }
    if (tid == 1023) rowptr[n] = part[1023];
}
__global__ void scatter_edges(const int* __restrict__ src, const int* __restrict__ dst,
                              const float* __restrict__ ew, int* __restrict__ ofs,
                              int* __restrict__ ssrc, float* __restrict__ sew,
                              int* __restrict__ seid) {
    int e = blockIdx.x * blockDim.x + threadIdx.x;
    if (e < N_EDGES) {
        int pos = atomicAdd(&ofs[dst[e]], 1);
        ssrc[pos] = src[e];
        sew[pos]  = ew[e];
        seid[pos] = e;
    }
}
__global__ void scatter_box(const int* __restrict__ bbox, int* __restrict__ ofs,
                            int* __restrict__ snode) {
    int i = blockIdx.x * blockDim.x + threadIdx.x;
    if (i < N_NODES) {
        int pos = atomicAdd(&ofs[bbox[i]], 1);
        snode[pos] = i;
    }
}

// ---------------------------------------------------------------------------
// Box mean via CSR (no atomics). Emits fp32 into out_super and bf16 fsmean.
// ---------------------------------------------------------------------------
__global__ __launch_bounds__(256) void box_mean_csr(
    const unsigned short* __restrict__ fsbf, const int* __restrict__ bptr,
    const int* __restrict__ snode, float* __restrict__ out_super,
    unsigned short* __restrict__ fsmeanb)
{
    const int b = blockIdx.x >> 2;
    const int c = ((blockIdx.x & 3) << 8) + threadIdx.x;
    const int s0 = bptr[b], s1 = bptr[b + 1];
    float sum = 0.f;
    for (int s = s0; s < s1; ++s)
        sum += bf2f(fsbf[(long)snode[s] * FD + c]);
    const float mean = sum / fmaxf((float)(s1 - s0), 1.f);
    out_super[(long)b * OUT_STRIDE + HID + c] = mean;
    fsmeanb[(long)b * FD + c] = f2bf(mean);
}

// ---------------------------------------------------------------------------
extern "C" void kernel_launch(void* const* d_in, const int* in_sizes, int n_in,
                              void* d_out, int out_size, void* d_ws, size_t ws_size,
                              hipStream_t stream) {
    const float* x      = (const float*)d_in[0];
    const int*   edges  = (const int*)d_in[1];
    const float* ew     = (const float*)d_in[2];
    const float* ea     = (const float*)d_in[3];
    const int*   bbox   = (const int*)d_in[4];
    const float* W_msg0 = (const float*)d_in[6];
    const float* b_msg0 = (const float*)d_in[7];
    const float* W_sup0 = (const float*)d_in[8];
    const float* b_sup0 = (const float*)d_in[9];
    const float* W_msg  = (const float*)d_in[10];
    const float* b_msg  = (const float*)d_in[11];
    const float* W_sup  = (const float*)d_in[12];
    const float* b_sup  = (const float*)d_in[13];
    const float* W_fuse = (const float*)d_in[14];
    const float* b_fuse = (const float*)d_in[15];
    const float* W_fsup = (const float*)d_in[16];
    const float* b_fsup = (const float*)d_in[17];

    float* out       = (float*)d_out;
    float* out_super = out + (long)N_NODES * OUT_STRIDE;

    // ---- workspace layout ----
    char* w = (char*)d_ws;
    auto alloc = [&](size_t bytes) { char* p = w; w += (bytes + 63) & ~63ULL; return p; };
    unsigned short* fsbf    = (unsigned short*)alloc((size_t)N_NODES * FD * 2);
    unsigned short* nfbf    = (unsigned short*)alloc((size_t)N_NODES * FD * 2);
    unsigned short* pq      = (unsigned short*)alloc((size_t)N_NODES * 512 * 2);
    unsigned short* xb      = (unsigned short*)alloc((size_t)N_NODES * CIN * 2);
    unsigned short* eab     = (unsigned short*)alloc((size_t)N_EDGES * A_DIM * 2);
    unsigned short* wpq0    = (unsigned short*)alloc((size_t)512 * CIN * 2);
    unsigned short* wpq     = (unsigned short*)alloc((size_t)3 * 512 * CCH * 2);
    unsigned short* wtr     = (unsigned short*)alloc((size_t)4 * 256 * 32 * 2);
    unsigned short* wt_sup0 = (unsigned short*)alloc((size_t)256 * 320 * 2);
    unsigned short* wt_sup  = (unsigned short*)alloc((size_t)3 * 256 * 512 * 2);
    unsigned short* wt_fuse = (unsigned short*)alloc((size_t)1024 * 1024 * 2);
    unsigned short* wt_fsup = (unsigned short*)alloc((size_t)1024 * 1024 * 2);
    unsigned short* fsmeanb = (unsigned short*)alloc((size_t)NBOX * FD * 2);
    float* sew        = (float*)alloc((size_t)N_EDGES * 4);
    int* cnt          = (int*)alloc((size_t)(N_NODES + 1) * 4);
    int* rowptr       = (int*)alloc((size_t)(N_NODES + 1) * 4);
    int* ofs          = (int*)alloc((size_t)(N_NODES + 1) * 4);
    int* ssrc         = (int*)alloc((size_t)N_EDGES * 4);
    int* seid         = (int*)alloc((size_t)N_EDGES * 4);
    int* bcnt         = (int*)alloc(129 * 4);
    int* bptr         = (int*)alloc(129 * 4);
    int* bofs         = (int*)alloc(129 * 4);
    int* snode        = (int*)alloc((size_t)N_NODES * 4);

    const int* srcp = edges;
    const int* dstp = edges + N_EDGES;

    // ---- input bf16 conversion ----
    f32_to_bf16<<<(N_NODES * CIN / 4 + 255) / 256, 256, 0, stream>>>(x, xb, N_NODES * CIN / 4);
    f32_to_bf16<<<(N_EDGES * A_DIM / 4 + 255) / 256, 256, 0, stream>>>(ea, eab, N_EDGES * A_DIM / 4);

    // ---- weight prep ----
    wpq_prep<<<(512 * CIN + 255) / 256, 256, 0, stream>>>(W_msg0, wpq0, CIN);
    wpq_prep3<<<dim3((512 * CCH + 255) / 256, 3), 256, 0, stream>>>(W_msg, wpq);
    wtr_prep<<<dim3((32 * 256 + 255) / 256, 4), 256, 0, stream>>>(W_msg0, W_msg, wtr);
    transpose_w<<<(320 * 256 + 255) / 256, 256, 0, stream>>>(W_sup0, wt_sup0, 320, 256);
    transpose_w3<<<dim3((512 * 256 + 255) / 256, 3), 256, 0, stream>>>(W_sup, wt_sup);
    transpose_w<<<(1024 * 1024 + 255) / 256, 256, 0, stream>>>(W_fuse, wt_fuse, 1024, 1024);
    transpose_w<<<(1024 * 1024 + 255) / 256, 256, 0, stream>>>(W_fsup, wt_fsup, 1024, 1024);

    // ---- CSR build (edges by dst; nodes by box) ----
    zero_int<<<(N_NODES + 256) / 256, 256, 0, stream>>>(cnt, N_NODES + 1);
    zero_int<<<1, 256, 0, stream>>>(bcnt, 129);
    hist_kernel<<<(N_EDGES + 255) / 256, 256, 0, stream>>>(dstp, N_EDGES, cnt);
    hist_kernel<<<(N_NODES + 255) / 256, 256, 0, stream>>>(bbox, N_NODES, bcnt);
    scan_kernel<<<1, 1024, 0, stream>>>(cnt, rowptr, ofs, N_NODES);
    scan_kernel<<<1, 1024, 0, stream>>>(bcnt, bptr, bofs, NBOX);
    scatter_edges<<<(N_EDGES + 255) / 256, 256, 0, stream>>>(srcp, dstp, ew, ofs, ssrc, sew, seid);
    scatter_box<<<(N_NODES + 255) / 256, 256, 0, stream>>>(bbox, bofs, snode);

    const int GRB = (N_NODES + 127) / 128;   // 157
    const int GEB = (N_EDGES + 127) / 128;   // 782
    unsigned short* Rb = (unsigned short*)out;   // R scratch in out[:,0:1024)

    // ---- head block ----
    mfma_dense<<<GRB * 4, 256, 0, stream>>>(xb, CIN, 0, CIN, nullptr,
        nullptr, 0, 0, wpq0, nullptr, 0,
        nullptr, 0, 0, pq, 512, 0, 0, N_NODES, CIN, 4);
    mfma_dense<<<GEB * 2, 256, 0, stream>>>(eab, A_DIM, 0, A_DIM, seid,
        nullptr, 0, 0, wtr, nullptr, 0,
        nullptr, 0, 0, Rb, 0, 0, 1, N_EDGES, A_DIM, 2);
    agg_kernel<<<(N_NODES + 3) / 4, 256, 0, stream>>>(pq, rowptr, ssrc, sew, out,
                                                      b_msg0, out, HID, -1, nfbf, 0);
    mfma_dense<<<GRB * 2, 256, 0, stream>>>(nfbf, FD, 0, CCH, nullptr,
        xb, CIN, 0, wt_sup0, b_sup0, 1,
        nullptr, 0, 0, fsbf, FD, 0, 0, N_NODES, CCH + CIN, 2);

    // ---- ResBlocks ----
    for (int i = 0; i < 3; ++i) {
        const int fi = HID + CCH * i, fo = HID + CCH * (i + 1);
        mfma_dense<<<GRB * 4, 256, 0, stream>>>(nfbf, FD, CCH * i, CCH, nullptr,
            nullptr, 0, 0, wpq + (long)i * 512 * CCH, nullptr, 0,
            nullptr, 0, 0, pq, 512, 0, 0, N_NODES, CCH, 4);
        mfma_dense<<<GEB * 2, 256, 0, stream>>>(eab, A_DIM, 0, A_DIM, seid,
            nullptr, 0, 0, wtr + (long)(i + 1) * 256 * 32, nullptr, 0,
            nullptr, 0, 0, Rb, 0, 0, 1, N_EDGES, A_DIM, 2);
        agg_kernel<<<(N_NODES + 3) / 4, 256, 0, stream>>>(pq, rowptr, ssrc, sew, out,
                                                          b_msg + i * CCH, out, fo, fi,
                                                          nfbf, CCH * (i + 1));
        mfma_dense<<<GRB * 2, 256, 0, stream>>>(nfbf, FD, CCH * (i + 1), CCH, nullptr,
            fsbf, FD, CCH * i, wt_sup + (long)i * 256 * 512, b_sup + i * CCH, 1,
            nullptr, 0, 0, fsbf, FD, CCH * (i + 1), 0, N_NODES, 2 * CCH, 2);
    }

    // ---- fusion ----
    mfma_dense<<<GRB * 8, 256, 0, stream>>>(nfbf, FD, 0, FD, nullptr,
        nullptr, 0, 0, wt_fuse, b_fuse, 1,
        out, OUT_STRIDE, 0, nullptr, 0, 0, 0, N_NODES, FD, 8);

    // ---- super path ----
    box_mean_csr<<<NBOX * 4, 256, 0, stream>>>(fsbf, bptr, snode, out_super, fsmeanb);
    mfma_dense<<<8, 256, 0, stream>>>(fsmeanb, FD, 0, FD, nullptr,
        nullptr, 0, 0, wt_fsup, b_fsup, 1,
        out_super, OUT_STRIDE, 0, nullptr, 0, 0, 0, NBOX, FD, 8);
}